// Round 2
// baseline (109.151 us; speedup 1.0000x reference)
//
#include <hip/hip_runtime.h>
#include <hip/hip_cooperative_groups.h>

namespace cg = cooperative_groups;

#define N_NODES 100000
#define N_EDGES 1600000
#define GRID    1024
#define BLOCK   256
#define NTHR    (GRID * BLOCK)

__device__ __forceinline__ float fold_c(const float* __restrict__ b1,
                                        const float* __restrict__ W2,
                                        const float* __restrict__ b2) {
    float c = b2[0];
#pragma unroll
    for (int k = 0; k < 16; ++k) c += b1[k] * W2[k];
    return c;
}

// int64 edges (LE) have all odd 32-bit words == 0 (values < 2^31, non-negative).
// int32 edges: odd words are real indices; P(64 random indices all zero) = 0.
__device__ __forceinline__ bool detect_is64(const int* __restrict__ e32, int t) {
    int w = e32[2 * (t & 63) + 1];
    unsigned long long m = __ballot(w != 0);
    return m == 0ULL;
}

__device__ __forceinline__ void node_pass(const float* __restrict__ h1,
                                          const float* __restrict__ h2,
                                          const float* __restrict__ wf,  // LDS, 256 floats
                                          float* __restrict__ ssrc, float* __restrict__ sdst,
                                          int t, int bid, int nblocks) {
    const int li = t & 15;
    const int g  = t >> 4;
    const float4* wf4 = (const float4*)wf;
    const float4 ws1 = wf4[li];        // w[0:64)    pairs h1 (src half)
    const float4 ws2 = wf4[16 + li];   // w[64:128)  pairs h2 (src half)
    const float4 wd1 = wf4[32 + li];   // w[128:192) pairs h1 (dst half)
    const float4 wd2 = wf4[48 + li];   // w[192:256) pairs h2 (dst half)

    for (int node = bid * 16 + g; node < N_NODES; node += nblocks * 16) {
        const float4 a = ((const float4*)(h1 + (size_t)node * 64))[li];
        const float4 b = ((const float4*)(h2 + (size_t)node * 64))[li];
        float ps = a.x * ws1.x + a.y * ws1.y + a.z * ws1.z + a.w * ws1.w
                 + b.x * ws2.x + b.y * ws2.y + b.z * ws2.z + b.w * ws2.w;
        float pd = a.x * wd1.x + a.y * wd1.y + a.z * wd1.z + a.w * wd1.w
                 + b.x * wd2.x + b.y * wd2.y + b.z * wd2.z + b.w * wd2.w;
#pragma unroll
        for (int off = 1; off < 16; off <<= 1) {
            ps += __shfl_xor(ps, off);
            pd += __shfl_xor(pd, off);
        }
        if (li == 0) { ssrc[node] = ps; sdst[node] = pd; }
    }
}

__global__ void fused_kernel(const float* __restrict__ h1, const float* __restrict__ h2,
                             const float* __restrict__ W1, const float* __restrict__ b1,
                             const float* __restrict__ W2, const float* __restrict__ b2,
                             const void* __restrict__ edges,
                             float* __restrict__ ssrc, float* __restrict__ sdst,
                             float* __restrict__ out) {
    __shared__ float wf[256];
    const int t = threadIdx.x;
    {
        float acc = 0.f;
#pragma unroll
        for (int k = 0; k < 16; ++k) acc += W1[t * 16 + k] * W2[k];
        wf[t] = acc;
    }
    const float c = fold_c(b1, W2, b2);
    const int* e32 = (const int*)edges;
    const bool is64 = detect_is64(e32, t);
    __syncthreads();

    node_pass(h1, h2, wf, ssrc, sdst, t, blockIdx.x, GRID);

    cg::this_grid().sync();

    const int tid = blockIdx.x * BLOCK + t;
    if (is64) {
        const long long* e64 = (const long long*)edges;
        for (int e = tid; e < N_EDGES; e += NTHR) {
            int s = (int)e64[e];
            int d = (int)e64[N_EDGES + e];
            out[e] = ssrc[s] + sdst[d] + c;
        }
    } else {
        for (int e = tid; e < N_EDGES; e += NTHR) {
            int s = e32[e];
            int d = e32[N_EDGES + e];
            out[e] = ssrc[s] + sdst[d] + c;
        }
    }
}

// ---- non-cooperative fallback (2 kernels) ----
__global__ void node_kernel(const float* __restrict__ h1, const float* __restrict__ h2,
                            const float* __restrict__ W1, const float* __restrict__ W2,
                            float* __restrict__ ssrc, float* __restrict__ sdst) {
    __shared__ float wf[256];
    const int t = threadIdx.x;
    float acc = 0.f;
#pragma unroll
    for (int k = 0; k < 16; ++k) acc += W1[t * 16 + k] * W2[k];
    wf[t] = acc;
    __syncthreads();
    node_pass(h1, h2, wf, ssrc, sdst, t, blockIdx.x, gridDim.x);
}

__global__ void edge_kernel(const void* __restrict__ edges,
                            const float* __restrict__ ssrc, const float* __restrict__ sdst,
                            const float* __restrict__ b1, const float* __restrict__ W2,
                            const float* __restrict__ b2,
                            float* __restrict__ out) {
    const int e = blockIdx.x * blockDim.x + threadIdx.x;  // 6250*256 = 1.6M exact
    const float c = fold_c(b1, W2, b2);
    const int* e32 = (const int*)edges;
    const bool is64 = detect_is64(e32, threadIdx.x);
    int s, d;
    if (is64) {
        const long long* e64 = (const long long*)edges;
        s = (int)e64[e];
        d = (int)e64[N_EDGES + e];
    } else {
        s = e32[e];
        d = e32[N_EDGES + e];
    }
    out[e] = ssrc[s] + sdst[d] + c;
}

extern "C" void kernel_launch(void* const* d_in, const int* in_sizes, int n_in,
                              void* d_out, int out_size, void* d_ws, size_t ws_size,
                              hipStream_t stream) {
    const float* h1 = (const float*)d_in[0];
    const float* h2 = (const float*)d_in[1];
    const float* W1 = (const float*)d_in[2];
    const float* b1 = (const float*)d_in[3];
    const float* W2 = (const float*)d_in[4];
    const float* b2 = (const float*)d_in[5];
    const void*  edges = d_in[6];

    float* ssrc = (float*)d_ws;
    float* sdst = ssrc + N_NODES;
    float* out  = (float*)d_out;

    void* args[] = {(void*)&h1, (void*)&h2, (void*)&W1, (void*)&b1, (void*)&W2,
                    (void*)&b2, (void*)&edges, (void*)&ssrc, (void*)&sdst, (void*)&out};
    hipError_t err = hipLaunchCooperativeKernel((void*)fused_kernel, dim3(GRID), dim3(BLOCK),
                                                args, 0, stream);
    if (err != hipSuccess) {
        // fallback: two plain kernels
        node_kernel<<<N_NODES / 16, 256, 0, stream>>>(h1, h2, W1, W2, ssrc, sdst);
        edge_kernel<<<N_EDGES / 256, 256, 0, stream>>>(edges, ssrc, sdst, b1, W2, b2, out);
    }
}

// Round 3
// 32.165 us; speedup vs baseline: 3.3934x; 3.3934x over previous
//
#include <hip/hip_runtime.h>

#define N_NODES 100000
#define N_EDGES 1600000

// ---------- kernel 1: per-node scalars (prep folded in) ----------
// s_src[n] = x[n] . w[0:128], s_dst[n] = x[n] . w[128:256], w = W1@W2
__global__ __launch_bounds__(256) void node_kernel(
        const float* __restrict__ h1, const float* __restrict__ h2,
        const float* __restrict__ W1, const float* __restrict__ W2,
        float* __restrict__ ssrc, float* __restrict__ sdst) {
    __shared__ float wf[256];
    const int t = threadIdx.x;
    {
        float acc = 0.f;
#pragma unroll
        for (int k = 0; k < 16; ++k) acc += W1[t * 16 + k] * W2[k];
        wf[t] = acc;
    }
    __syncthreads();

    const int li = t & 15;
    const int g  = t >> 4;
    const int node = blockIdx.x * 16 + g;      // 6250 * 16 = 100000 exact

    const float4* wf4 = (const float4*)wf;
    const float4 ws1 = wf4[li];        // w[0:64)    pairs h1 (src half)
    const float4 ws2 = wf4[16 + li];   // w[64:128)  pairs h2 (src half)
    const float4 wd1 = wf4[32 + li];   // w[128:192) pairs h1 (dst half)
    const float4 wd2 = wf4[48 + li];   // w[192:256) pairs h2 (dst half)

    const float4 a = ((const float4*)(h1 + (size_t)node * 64))[li];
    const float4 b = ((const float4*)(h2 + (size_t)node * 64))[li];

    float ps = a.x * ws1.x + a.y * ws1.y + a.z * ws1.z + a.w * ws1.w
             + b.x * ws2.x + b.y * ws2.y + b.z * ws2.z + b.w * ws2.w;
    float pd = a.x * wd1.x + a.y * wd1.y + a.z * wd1.z + a.w * wd1.w
             + b.x * wd2.x + b.y * wd2.y + b.z * wd2.z + b.w * wd2.w;

#pragma unroll
    for (int off = 1; off < 16; off <<= 1) {
        ps += __shfl_xor(ps, off);
        pd += __shfl_xor(pd, off);
    }
    if (li == 0) { ssrc[node] = ps; sdst[node] = pd; }
}

// ---------- kernel 2: edge gather + add (c-fold + dtype-detect inlined) ----------
__global__ __launch_bounds__(256) void edge_kernel(
        const void* __restrict__ edges,
        const float* __restrict__ ssrc, const float* __restrict__ sdst,
        const float* __restrict__ b1, const float* __restrict__ W2,
        const float* __restrict__ b2,
        float* __restrict__ out) {
    const int t   = threadIdx.x;
    const int tid = blockIdx.x * 256 + t;      // 3125 * 256 * 2 = 1.6M edges exact

    float c = b2[0];
#pragma unroll
    for (int k = 0; k < 16; ++k) c += b1[k] * W2[k];

    // int64 edges (LE, values in [0,1e5)) have all odd 32-bit words == 0;
    // int32 edges have random indices there -> ballot over 64 samples decides.
    const int* e32 = (const int*)edges;
    const bool is64 = (__ballot(e32[2 * (t & 63) + 1] != 0) == 0ULL);

    int s0, d0, s1, d1;
    if (is64) {
        const long2* es = (const long2*)edges;                    // src row
        const long2* ed = es + (N_EDGES / 2);                     // dst row
        long2 se = es[tid];
        long2 de = ed[tid];
        s0 = (int)se.x; s1 = (int)se.y;
        d0 = (int)de.x; d1 = (int)de.y;
    } else {
        const int2* es = (const int2*)edges;
        const int2* ed = es + (N_EDGES / 2);
        int2 se = es[tid];
        int2 de = ed[tid];
        s0 = se.x; s1 = se.y;
        d0 = de.x; d1 = de.y;
    }

    float2 r;
    r.x = ssrc[s0] + sdst[d0] + c;
    r.y = ssrc[s1] + sdst[d1] + c;
    ((float2*)out)[tid] = r;
}

extern "C" void kernel_launch(void* const* d_in, const int* in_sizes, int n_in,
                              void* d_out, int out_size, void* d_ws, size_t ws_size,
                              hipStream_t stream) {
    const float* h1 = (const float*)d_in[0];
    const float* h2 = (const float*)d_in[1];
    const float* W1 = (const float*)d_in[2];
    const float* b1 = (const float*)d_in[3];
    const float* W2 = (const float*)d_in[4];
    const float* b2 = (const float*)d_in[5];
    const void*  edges = d_in[6];

    float* ssrc = (float*)d_ws;
    float* sdst = ssrc + N_NODES;
    float* out  = (float*)d_out;

    node_kernel<<<N_NODES / 16, 256, 0, stream>>>(h1, h2, W1, W2, ssrc, sdst);
    edge_kernel<<<N_EDGES / 512, 256, 0, stream>>>(edges, ssrc, sdst, b1, W2, b2, out);
}

// Round 5
// 31.292 us; speedup vs baseline: 3.4881x; 1.0279x over previous
//
#include <hip/hip_runtime.h>

#define N_NODES 100000
#define N_EDGES 1600000
#define GRID_N  1250          // 1250 blocks * 16 nodes = 20000 nodes/iter, 5 iters exact

typedef float  f32x4 __attribute__((ext_vector_type(4)));
typedef float  f32x2 __attribute__((ext_vector_type(2)));
typedef int    i32x2 __attribute__((ext_vector_type(2)));
typedef long long i64x2 __attribute__((ext_vector_type(2)));

// ---------- kernel 1: per-node scalars (W-fold amortized via grid-stride) ----------
// s_src[n] = x[n] . w[0:128], s_dst[n] = x[n] . w[128:256], w = W1@W2
__global__ __launch_bounds__(256) void node_kernel(
        const float* __restrict__ h1, const float* __restrict__ h2,
        const float* __restrict__ W1, const float* __restrict__ W2,
        float* __restrict__ ssrc, float* __restrict__ sdst) {
    __shared__ float wf[256];
    const int t = threadIdx.x;
    {
        float acc = 0.f;
#pragma unroll
        for (int k = 0; k < 16; ++k) acc += W1[t * 16 + k] * W2[k];
        wf[t] = acc;
    }
    __syncthreads();

    const int li = t & 15;
    const int g  = t >> 4;

    const f32x4* wf4 = (const f32x4*)wf;
    const f32x4 ws1 = wf4[li];        // w[0:64)    pairs h1 (src half)
    const f32x4 ws2 = wf4[16 + li];   // w[64:128)  pairs h2 (src half)
    const f32x4 wd1 = wf4[32 + li];   // w[128:192) pairs h1 (dst half)
    const f32x4 wd2 = wf4[48 + li];   // w[192:256) pairs h2 (dst half)

#pragma unroll
    for (int it = 0; it < 5; ++it) {
        const int node = it * (GRID_N * 16) + blockIdx.x * 16 + g;

        const f32x4 a = __builtin_nontemporal_load(
            (const f32x4*)(h1 + (size_t)node * 64) + li);
        const f32x4 b = __builtin_nontemporal_load(
            (const f32x4*)(h2 + (size_t)node * 64) + li);

        float ps = a.x * ws1.x + a.y * ws1.y + a.z * ws1.z + a.w * ws1.w
                 + b.x * ws2.x + b.y * ws2.y + b.z * ws2.z + b.w * ws2.w;
        float pd = a.x * wd1.x + a.y * wd1.y + a.z * wd1.z + a.w * wd1.w
                 + b.x * wd2.x + b.y * wd2.y + b.z * wd2.z + b.w * wd2.w;

#pragma unroll
        for (int off = 1; off < 16; off <<= 1) {
            ps += __shfl_xor(ps, off);
            pd += __shfl_xor(pd, off);
        }
        if (li == 0) { ssrc[node] = ps; sdst[node] = pd; }
    }
}

// ---------- kernel 2: edge gather + add ----------
__global__ __launch_bounds__(256) void edge_kernel(
        const void* __restrict__ edges,
        const float* __restrict__ ssrc, const float* __restrict__ sdst,
        const float* __restrict__ b1, const float* __restrict__ W2,
        const float* __restrict__ b2,
        float* __restrict__ out) {
    const int t   = threadIdx.x;
    const int tid = blockIdx.x * 256 + t;      // 3125 * 256 * 2 = 1.6M edges exact

    float c = b2[0];
#pragma unroll
    for (int k = 0; k < 16; ++k) c += b1[k] * W2[k];

    // int64 edges (LE, values in [0,1e5)) have all odd 32-bit words == 0;
    // int32 edges have random indices there -> ballot over 64 samples decides.
    const int* e32 = (const int*)edges;
    const bool is64 = (__ballot(e32[2 * (t & 63) + 1] != 0) == 0ULL);

    int s0, d0, s1, d1;
    if (is64) {
        const i64x2* es = (const i64x2*)edges;                    // src row
        const i64x2* ed = es + (N_EDGES / 2);                     // dst row
        i64x2 se = __builtin_nontemporal_load(es + tid);
        i64x2 de = __builtin_nontemporal_load(ed + tid);
        s0 = (int)se.x; s1 = (int)se.y;
        d0 = (int)de.x; d1 = (int)de.y;
    } else {
        const i32x2* es = (const i32x2*)edges;
        const i32x2* ed = es + (N_EDGES / 2);
        i32x2 se = __builtin_nontemporal_load(es + tid);
        i32x2 de = __builtin_nontemporal_load(ed + tid);
        s0 = se.x; s1 = se.y;
        d0 = de.x; d1 = de.y;
    }

    f32x2 r;
    r.x = ssrc[s0] + sdst[d0] + c;
    r.y = ssrc[s1] + sdst[d1] + c;
    __builtin_nontemporal_store(r, (f32x2*)out + tid);
}

extern "C" void kernel_launch(void* const* d_in, const int* in_sizes, int n_in,
                              void* d_out, int out_size, void* d_ws, size_t ws_size,
                              hipStream_t stream) {
    const float* h1 = (const float*)d_in[0];
    const float* h2 = (const float*)d_in[1];
    const float* W1 = (const float*)d_in[2];
    const float* b1 = (const float*)d_in[3];
    const float* W2 = (const float*)d_in[4];
    const float* b2 = (const float*)d_in[5];
    const void*  edges = d_in[6];

    float* ssrc = (float*)d_ws;
    float* sdst = ssrc + N_NODES;
    float* out  = (float*)d_out;

    node_kernel<<<GRID_N, 256, 0, stream>>>(h1, h2, W1, W2, ssrc, sdst);
    edge_kernel<<<N_EDGES / 512, 256, 0, stream>>>(edges, ssrc, sdst, b1, W2, b2, out);
}